// Round 6
// baseline (406.058 us; speedup 1.0000x reference)
//
#include <hip/hip_runtime.h>
#include <stdint.h>

#define E_  8
#define H_  768
#define I_  1152
#define T_  4096
#define F2_ (2*I_)   // 2304
#define RBMAX 104    // worst-case total 128-row blocks: <=72 expert + 32 shared

typedef unsigned short u16;
typedef __attribute__((ext_vector_type(8))) __bf16 bf16x8;
typedef __attribute__((ext_vector_type(4))) float floatx4;

typedef const void __attribute__((address_space(1))) as1_void;
typedef void __attribute__((address_space(3))) as3_void;

__device__ __forceinline__ void gld16(void* lds, const void* g) {
  __builtin_amdgcn_global_load_lds((as1_void*)g, (as3_void*)lds, 16, 0, 0);
}

__device__ __forceinline__ u16 f2bf(float f) {
  union { float f; unsigned int i; } v; v.f = f;
  unsigned int r = v.i + 0x7FFF + ((v.i >> 16) & 1);  // round-to-nearest-even
  return (u16)(r >> 16);
}

// ================= fused prep: gate + converts + transposes =================
// blocks [0,1024): gate (4 tokens each)
// blocks [1024,3616): convert sWi,sWo fp32->bf16
// blocks [3616,7072): transpose Wi (H x F2 -> F2 x H) per expert
// blocks [7072,8800): transpose Wo (I x H -> H x I) per expert
__device__ __forceinline__ void transpose_tile(const float* __restrict__ s,
                                               u16* __restrict__ d, int R, int C,
                                               int r0, int c0, u16 (*tile)[65], int tid) {
  int tx = tid & 63, ty = tid >> 6;   // 256 threads: 4 rows/pass
  #pragma unroll
  for (int k = 0; k < 64; k += 4)
    tile[ty + k][tx] = f2bf(s[(long)(r0 + ty + k) * C + (c0 + tx)]);
  __syncthreads();
  #pragma unroll
  for (int k = 0; k < 64; k += 4)
    d[(long)(c0 + ty + k) * R + (r0 + tx)] = tile[tx][ty + k];
}

__global__ void prep_kernel(const float* __restrict__ x, const float* __restrict__ gw,
                            const float* __restrict__ bias,
                            int* __restrict__ top2e, float* __restrict__ top2w,
                            u16* __restrict__ xb,
                            const float* __restrict__ sWi, u16* __restrict__ sWib,
                            const float* __restrict__ sWo, u16* __restrict__ sWob,
                            const float* __restrict__ Wi, u16* __restrict__ WiT,
                            const float* __restrict__ Wo, u16* __restrict__ WoT) {
  __shared__ u16 tile[64][65];
  int b = blockIdx.x, tid = threadIdx.x;
  if (b < 1024) {
    // ---- gate: one wave per token ----
    int t    = b * 4 + (tid >> 6);
    int lane = tid & 63;
    float acc[E_];
    #pragma unroll
    for (int e = 0; e < E_; e++) acc[e] = 0.f;
    #pragma unroll
    for (int i = 0; i < H_ / 256; i++) {
      int c = i * 256 + lane * 4;
      float4 xv = *(const float4*)(x + (long)t * H_ + c);
      ushort4 u;
      u.x = f2bf(xv.x); u.y = f2bf(xv.y); u.z = f2bf(xv.z); u.w = f2bf(xv.w);
      *(ushort4*)(xb + (long)t * H_ + c) = u;
      #pragma unroll
      for (int e = 0; e < E_; e++) {
        float4 g = *(const float4*)(gw + e * H_ + c);
        acc[e] += xv.x * g.x + xv.y * g.y + xv.z * g.z + xv.w * g.w;
      }
    }
    #pragma unroll
    for (int e = 0; e < E_; e++) {
      #pragma unroll
      for (int s = 32; s > 0; s >>= 1) acc[e] += __shfl_xor(acc[e], s);
    }
    if (lane == 0) {
      float logits[E_], sel[E_];
      #pragma unroll
      for (int e = 0; e < E_; e++) {
        logits[e] = 1.f / (1.f + expf(-acc[e]));
        sel[e]    = logits[e] + bias[e];
      }
      int i0 = 0;
      #pragma unroll
      for (int e = 1; e < E_; e++) if (sel[e] > sel[i0]) i0 = e;
      int i1 = (i0 == 0) ? 1 : 0;
      #pragma unroll
      for (int e = 0; e < E_; e++) if (e != i0 && sel[e] > sel[i1]) i1 = e;
      float w0 = logits[i0], w1 = logits[i1], s = w0 + w1;
      top2e[t * 2 + 0] = i0;  top2w[t * 2 + 0] = w0 / s;
      top2e[t * 2 + 1] = i1;  top2w[t * 2 + 1] = w1 / s;
    }
  } else if (b < 3616) {
    int i = (b - 1024) * 1024 + tid * 4;
    const int n1 = F2_ * H_;
    const float* s; u16* d;
    if (i < n1) { s = sWi + i; d = sWib + i; }
    else        { s = sWo + (i - n1); d = sWob + (i - n1); }
    float4 v = *(const float4*)s;
    ushort4 u;
    u.x = f2bf(v.x); u.y = f2bf(v.y); u.z = f2bf(v.z); u.w = f2bf(v.w);
    *(ushort4*)d = u;
  } else if (b < 7072) {
    int idx = b - 3616;
    int bx = idx % 36, tmp = idx / 36;
    int by = tmp % 12, bz = tmp / 12;
    transpose_tile(Wi + (long)bz * H_ * F2_, WiT + (long)bz * F2_ * H_,
                   H_, F2_, by * 64, bx * 64, tile, tid);
  } else {
    int idx = b - 7072;
    int bx = idx % 12, tmp = idx / 12;
    int by = tmp % 18, bz = tmp / 18;
    transpose_tile(Wo + (long)bz * I_ * H_, WoT + (long)bz * H_ * I_,
                   I_, H_, by * 64, bx * 64, tile, tid);
  }
}

// ---------------- build lists: 8 blocks (one per expert), zero atomics ----------------
__global__ void build_lists(const int* __restrict__ top2e, const float* __restrict__ top2w,
                            int* __restrict__ counts, int* __restrict__ offs,
                            int* __restrict__ list, float* __restrict__ wlist,
                            int* __restrict__ pos, int* __restrict__ rbc) {
  __shared__ int scnt[4][E_];
  __shared__ int sq[4];
  __shared__ int soffs[E_];
  int e = blockIdx.x;
  int tid = threadIdx.x, w = tid >> 6, lane = tid & 63;
  const int Q = (2 * T_) / 4;

  int c8[E_];
  #pragma unroll
  for (int q = 0; q < E_; q++) c8[q] = 0;
  for (int i = tid; i < 2 * T_; i += 256) {
    int v = top2e[i];
    #pragma unroll
    for (int q = 0; q < E_; q++) c8[q] += (v == q);
  }
  int qstart = w * Q;
  int ce = 0;
  for (int i = qstart + lane; i < qstart + Q; i += 64) ce += (top2e[i] == e);
  #pragma unroll
  for (int q = 0; q < E_; q++)
    #pragma unroll
    for (int s = 32; s > 0; s >>= 1) c8[q] += __shfl_xor(c8[q], s);
  #pragma unroll
  for (int s = 32; s > 0; s >>= 1) ce += __shfl_xor(ce, s);
  if (lane == 0) {
    #pragma unroll
    for (int q = 0; q < E_; q++) scnt[w][q] = c8[q];
    sq[w] = ce;
  }
  __syncthreads();
  if (tid == 0) {
    int s = 0, rb = 0;
    if (e == 0) rbc[0] = 0;
    #pragma unroll
    for (int q = 0; q < E_; q++) {
      int tot = scnt[0][q] + scnt[1][q] + scnt[2][q] + scnt[3][q];
      soffs[q] = s;
      if (e == 0) {
        counts[q] = tot; offs[q] = s;
        rb += (tot + 127) / 128;
        rbc[q + 1] = rb;
      }
      s += tot;
    }
    if (e == 0) {
      counts[8] = T_; offs[8] = 2 * T_;
      rbc[9] = rb + T_ / 128;
    }
  }
  __syncthreads();
  int base = soffs[e];
  #pragma unroll
  for (int w2 = 0; w2 < 4; w2++) if (w2 < w) base += sq[w2];
  unsigned long long lt = (lane == 63) ? (~0ull >> 1) : ((1ull << lane) - 1);
  for (int i0 = qstart; i0 < qstart + Q; i0 += 64) {
    int s = i0 + lane;
    bool m = (top2e[s] == e);
    unsigned long long mask = __ballot(m);
    if (m) {
      int p = base + __popcll(mask & lt);
      list[p]  = s >> 1;
      wlist[p] = top2w[s];
      pos[s]   = p;
    }
    base += __popcll(mask);
  }
  for (int t = e * (T_ / 8) + tid; t < (e + 1) * (T_ / 8); t += 256) {
    list[2 * T_ + t]  = t;
    wlist[2 * T_ + t] = 1.f;
  }
}

// ---------------- GEMM1 (+fused SiLU): A via LDS, B streamed direct ----------------
// Compacted grid: id = r*24 + xblk (24 = 18 padded to mult of 8 -> id%8 = xblk%8).
__global__ __launch_bounds__(256, 2)
void gemm_act_all(const u16* __restrict__ A, const u16* __restrict__ WiT,
                  const u16* __restrict__ sWib, u16* __restrict__ act,
                  const int* __restrict__ list, const float* __restrict__ wlist,
                  const int* __restrict__ counts, const int* __restrict__ offsets,
                  const int* __restrict__ rbc) {
  __shared__ __align__(16) u16 As[128 * 64];

  int id = blockIdx.x;
  int r = id / 24, xblk = id - r * 24;
  if (xblk >= 18) return;
  if (r >= rbc[9]) return;
  int z = 0;
  while (r >= rbc[z + 1]) z++;
  int y = r - rbc[z];
  int cnt = counts[z], off = offsets[z];
  int row0 = y * 128;
  const u16* B = (z == 8) ? sWib : (WiT + (long)z * F2_ * H_);
  int n0 = xblk * 64;

  int tid  = threadIdx.x;
  int lane = tid & 63, wv = tid >> 6;
  int wr   = wv >> 1, wc = wv & 1;
  int half = lane & 15, quad = lane >> 4;

  // A staging: row rA+32n, physical chunk tid&7 holds logical chunk ^(rA&7)
  int rA  = tid >> 3;
  int lc8 = ((tid & 7) ^ (rA & 7)) * 8;
  const u16* ap[4];
  #pragma unroll
  for (int n = 0; n < 4; n++) {
    int rr = min(row0 + rA + n * 32, cnt - 1);
    ap[n] = A + (long)list[off + rr] * H_ + lc8;
  }
  // B fragment base addresses (direct global->reg)
  const u16* bb[2][2];
  #pragma unroll
  for (int h = 0; h < 2; h++)
    #pragma unroll
    for (int j = 0; j < 2; j++)
      bb[h][j] = B + (long)(h * I_ + n0 + wc * 32 + j * 16 + half) * H_ + quad * 8;

  floatx4 acc[2][4][2];
  #pragma unroll
  for (int q = 0; q < 2; q++)
    #pragma unroll
    for (int i = 0; i < 4; i++)
      #pragma unroll
      for (int j = 0; j < 2; j++) acc[q][i][j] = (floatx4)0.f;

  for (int k0 = 0; k0 < H_; k0 += 64) {
    bf16x8 bq[2][2][2];   // [kk][h][j]
    #pragma unroll
    for (int kk = 0; kk < 2; kk++)
      #pragma unroll
      for (int h = 0; h < 2; h++)
        #pragma unroll
        for (int j = 0; j < 2; j++)
          bq[kk][h][j] = *(const bf16x8*)(bb[h][j] + k0 + kk * 32);
    if (k0) __syncthreads();
    #pragma unroll
    for (int n = 0; n < 4; n++) gld16(As + (n * 256 + tid) * 8, ap[n] + k0);
    __syncthreads();
    #pragma unroll
    for (int kk = 0; kk < 2; kk++) {
      int cs = ((kk * 4 + quad) ^ (half & 7)) * 8;
      bf16x8 a[4];
      #pragma unroll
      for (int i = 0; i < 4; i++)
        a[i] = *(const bf16x8*)(As + (wr * 64 + i * 16 + half) * 64 + cs);
      #pragma unroll
      for (int i = 0; i < 4; i++)
        #pragma unroll
        for (int q = 0; q < 2; q++)
          #pragma unroll
          for (int j = 0; j < 2; j++)
            acc[q][i][j] = __builtin_amdgcn_mfma_f32_16x16x32_bf16(a[i], bq[kk][q][j], acc[q][i][j], 0, 0, 0);
    }
  }

  bool sh = (z == 8);
  #pragma unroll
  for (int i = 0; i < 4; i++) {
    #pragma unroll
    for (int rr = 0; rr < 4; rr++) {
      int g = row0 + wr * 64 + i * 16 + quad * 4 + rr;
      if (g < cnt) {
        float w = wlist[off + g];
        #pragma unroll
        for (int j = 0; j < 2; j++) {
          float va = acc[0][i][j][rr];
          float vb = acc[1][i][j][rr];
          float zz = sh ? va : vb;
          float o  = sh ? vb : va;
          float sg = zz / (1.f + expf(-zz));
          float v  = sg * o * w;
          int col  = n0 + wc * 32 + j * 16 + half;
          act[(long)(off + g) * I_ + col] = f2bf(v);
        }
      }
    }
  }
}

// ---------------- GEMM2: A (contiguous slot rows) via LDS, B direct ----------------
__global__ __launch_bounds__(256, 2)
void gemm_out_all(const u16* __restrict__ A, const u16* __restrict__ WoT,
                  const u16* __restrict__ sWob, float* __restrict__ out,
                  float* __restrict__ eobuf,
                  const int* __restrict__ counts, const int* __restrict__ offsets,
                  const int* __restrict__ rbc) {
  __shared__ __align__(16) u16 As[128 * 64];

  int id = blockIdx.x;
  int r = id >> 3, xblk = id & 7;
  if (xblk >= 6) return;
  if (r >= rbc[9]) return;
  int z = 0;
  while (r >= rbc[z + 1]) z++;
  int y = r - rbc[z];
  int cnt = counts[z], off = offsets[z];
  int row0 = y * 128;
  const u16* B = (z == 8) ? sWob : (WoT + (long)z * H_ * I_);
  int n0 = xblk * 128;

  int tid  = threadIdx.x;
  int lane = tid & 63, wv = tid >> 6;
  int wr   = wv >> 1, wc = wv & 1;
  int half = lane & 15, quad = lane >> 4;

  int rA  = tid >> 3;
  int lc8 = ((tid & 7) ^ (rA & 7)) * 8;
  const u16* ap[4];
  #pragma unroll
  for (int n = 0; n < 4; n++) {
    long rr = off + min(row0 + rA + n * 32, cnt - 1);
    ap[n] = A + rr * I_ + lc8;
  }
  const u16* bb[4];
  #pragma unroll
  for (int j = 0; j < 4; j++)
    bb[j] = B + (long)(n0 + wc * 64 + j * 16 + half) * I_ + quad * 8;

  floatx4 acc[4][4];
  #pragma unroll
  for (int i = 0; i < 4; i++)
    #pragma unroll
    for (int j = 0; j < 4; j++) acc[i][j] = (floatx4)0.f;

  for (int k0 = 0; k0 < I_; k0 += 64) {
    bf16x8 bq[2][4];
    #pragma unroll
    for (int kk = 0; kk < 2; kk++)
      #pragma unroll
      for (int j = 0; j < 4; j++)
        bq[kk][j] = *(const bf16x8*)(bb[j] + k0 + kk * 32);
    if (k0) __syncthreads();
    #pragma unroll
    for (int n = 0; n < 4; n++) gld16(As + (n * 256 + tid) * 8, ap[n] + k0);
    __syncthreads();
    #pragma unroll
    for (int kk = 0; kk < 2; kk++) {
      int cs = ((kk * 4 + quad) ^ (half & 7)) * 8;
      bf16x8 a[4];
      #pragma unroll
      for (int i = 0; i < 4; i++)
        a[i] = *(const bf16x8*)(As + (wr * 64 + i * 16 + half) * 64 + cs);
      #pragma unroll
      for (int i = 0; i < 4; i++)
        #pragma unroll
        for (int j = 0; j < 4; j++)
          acc[i][j] = __builtin_amdgcn_mfma_f32_16x16x32_bf16(a[i], bq[kk][j], acc[i][j], 0, 0, 0);
    }
  }

  bool sh = (z == 8);
  #pragma unroll
  for (int i = 0; i < 4; i++) {
    #pragma unroll
    for (int rr = 0; rr < 4; rr++) {
      int g = row0 + wr * 64 + i * 16 + quad * 4 + rr;
      if (g < cnt) {
        float* orow = sh ? (out + (long)g * H_) : (eobuf + (long)(off + g) * H_);
        #pragma unroll
        for (int j = 0; j < 4; j++) {
          int col = n0 + wc * 64 + j * 16 + half;
          orow[col] = acc[i][j][rr];
        }
      }
    }
  }
}

// ---------------- final: out[t] += eobuf[pos0[t]] + eobuf[pos1[t]] ----------------
__global__ void final_reduce(float* __restrict__ out, const float* __restrict__ eobuf,
                             const int* __restrict__ pos) {
  int gid = blockIdx.x * 256 + threadIdx.x;
  int t = gid / (H_ / 4), c = (gid % (H_ / 4)) * 4;
  int p0 = pos[t * 2], p1 = pos[t * 2 + 1];
  float4 a = *(const float4*)(out   + (long)t  * H_ + c);
  float4 b = *(const float4*)(eobuf + (long)p0 * H_ + c);
  float4 d = *(const float4*)(eobuf + (long)p1 * H_ + c);
  a.x += b.x + d.x; a.y += b.y + d.y; a.z += b.z + d.z; a.w += b.w + d.w;
  *(float4*)(out + (long)t * H_ + c) = a;
}

extern "C" void kernel_launch(void* const* d_in, const int* in_sizes, int n_in,
                              void* d_out, int out_size, void* d_ws, size_t ws_size,
                              hipStream_t stream) {
  const float* x      = (const float*)d_in[0];
  const float* gate_w = (const float*)d_in[1];
  const float* bias   = (const float*)d_in[2];
  const float* Wi     = (const float*)d_in[3];
  const float* Wo     = (const float*)d_in[4];
  const float* sWi    = (const float*)d_in[5];
  const float* sWo    = (const float*)d_in[6];
  float* out          = (float*)d_out;

  char* ws = (char*)d_ws;
  size_t o = 0;
  auto alloc = [&](size_t bytes) -> void* {
    o = (o + 255) & ~(size_t)255;
    void* p = ws + o;
    o += bytes;
    return p;
  };
  u16*   xb    = (u16*)  alloc((size_t)T_ * H_ * 2);
  u16*   sWib  = (u16*)  alloc((size_t)F2_ * H_ * 2);
  u16*   sWob  = (u16*)  alloc((size_t)H_ * I_ * 2);
  u16*   WiT   = (u16*)  alloc((size_t)E_ * F2_ * H_ * 2);   // 28.3 MB
  u16*   WoT   = (u16*)  alloc((size_t)E_ * H_ * I_ * 2);
  u16*   act   = (u16*)  alloc((size_t)3 * T_ * I_ * 2);
  int*   top2e = (int*)  alloc((size_t)T_ * 2 * 4);
  float* top2w = (float*)alloc((size_t)T_ * 2 * 4);
  int*   count = (int*)  alloc(9 * 4);
  int*   offs  = (int*)  alloc(9 * 4);
  int*   list  = (int*)  alloc((size_t)3 * T_ * 4);
  float* wlist = (float*)alloc((size_t)3 * T_ * 4);
  int*   pos   = (int*)  alloc((size_t)2 * T_ * 4);
  int*   rbc   = (int*)  alloc(16 * 4);
  // eobuf (8192*768*4 = 25.2 MB) aliases WiT (28.3 MB): WiT dead after gemm_act_all.
  float* eobuf = (float*)WiT;

  prep_kernel<<<8800, 256, 0, stream>>>(x, gate_w, bias, top2e, top2w, xb,
                                        sWi, sWib, sWo, sWob, Wi, WiT, Wo, WoT);
  build_lists<<<E_, 256, 0, stream>>>(top2e, top2w, count, offs, list, wlist, pos, rbc);

  gemm_act_all<<<RBMAX * 24, 256, 0, stream>>>(xb, WiT, sWib, act, list, wlist,
                                               count, offs, rbc);
  gemm_out_all<<<RBMAX * 8, 256, 0, stream>>>(act, WoT, sWob, out, eobuf,
                                              count, offs, rbc);
  final_reduce<<<(T_ * (H_ / 4)) / 256, 256, 0, stream>>>(out, eobuf, pos);
}

// Round 7
// 312.443 us; speedup vs baseline: 1.2996x; 1.2996x over previous
//
#include <hip/hip_runtime.h>
#include <stdint.h>

#define E_  8
#define H_  768
#define I_  1152
#define T_  4096
#define F2_ (2*I_)   // 2304
#define RBMAX 104    // worst-case total 128-row blocks: <=72 expert + 32 shared

typedef unsigned short u16;
typedef __attribute__((ext_vector_type(8))) __bf16 bf16x8;
typedef __attribute__((ext_vector_type(8))) unsigned short u16x8;
typedef __attribute__((ext_vector_type(4))) float floatx4;

typedef const void __attribute__((address_space(1))) as1_void;
typedef void __attribute__((address_space(3))) as3_void;

__device__ __forceinline__ void gld16(void* lds, const void* g) {
  __builtin_amdgcn_global_load_lds((as1_void*)g, (as3_void*)lds, 16, 0, 0);
}

__device__ __forceinline__ u16 f2bf(float f) {
  union { float f; unsigned int i; } v; v.f = f;
  unsigned int r = v.i + 0x7FFF + ((v.i >> 16) & 1);  // round-to-nearest-even
  return (u16)(r >> 16);
}

// ===== packed-B layout ("weight shuffle"): B(n,k), panel = (n>>4)*(K/32)+(k>>5),
// lane = (n&15) | (((k>>3)&3)<<4), elem = k&7; offset = (panel*64+lane)*8+elem.
// A wave's MFMA B-fragment load becomes base + lane*16B -> fully coalesced.

// pack from src fp32 (N rows, K cols) row-major: element (n,k) = src[n*K+k]
__device__ __forceinline__ void pack_direct(const float* __restrict__ src,
                                            u16* __restrict__ dst, int N, int K,
                                            int n0, int k0, int tid) {
  int n = tid & 63, kc2 = tid >> 6;
  int KT = K >> 5;
  #pragma unroll
  for (int pass = 0; pass < 2; pass++) {
    int kc = kc2 + pass * 4;
    int k  = k0 + kc * 8;
    const float* sp = src + (long)(n0 + n) * K + k;
    float4 v0 = *(const float4*)sp;
    float4 v1 = *(const float4*)(sp + 4);
    u16x8 u;
    u[0]=f2bf(v0.x); u[1]=f2bf(v0.y); u[2]=f2bf(v0.z); u[3]=f2bf(v0.w);
    u[4]=f2bf(v1.x); u[5]=f2bf(v1.y); u[6]=f2bf(v1.z); u[7]=f2bf(v1.w);
    long p = (long)((n0 + n) >> 4) * KT + (k >> 5);
    int lane = (n & 15) | ((kc & 3) << 4);
    *(u16x8*)(dst + (p * 64 + lane) * 8) = u;
  }
}

// pack from src fp32 (K rows, N cols) row-major: element (n,k) = src[k*N+n]
__device__ __forceinline__ void pack_transpose(const float* __restrict__ src,
                                               u16* __restrict__ dst, int N, int K,
                                               int n0, int k0, float (*tile)[65], int tid) {
  int cc = tid & 63, rr = tid >> 6;
  #pragma unroll
  for (int p = 0; p < 16; p++)
    tile[rr + p * 4][cc] = src[(long)(k0 + rr + p * 4) * N + n0 + cc];
  __syncthreads();
  int n = tid & 63, kc2 = tid >> 6;
  int KT = K >> 5;
  #pragma unroll
  for (int pass = 0; pass < 2; pass++) {
    int kc = kc2 + pass * 4;
    int k  = k0 + kc * 8;
    u16x8 u;
    #pragma unroll
    for (int e = 0; e < 8; e++) u[e] = f2bf(tile[kc * 8 + e][n]);
    long p = (long)((n0 + n) >> 4) * KT + (k >> 5);
    int lane = (n & 15) | ((kc & 3) << 4);
    *(u16x8*)(dst + (p * 64 + lane) * 8) = u;
  }
}

// ================= fused prep: gate + weight packing =================
// [0,1024): gate;  [1024,1456): sWi pack_direct;  [1456,1672): sWo pack_direct;
// [1672,5128): Wi pack_transpose;  [5128,6856): Wo pack_transpose.
__global__ void prep_kernel(const float* __restrict__ x, const float* __restrict__ gw,
                            const float* __restrict__ bias,
                            int* __restrict__ top2e, float* __restrict__ top2w,
                            u16* __restrict__ xb,
                            const float* __restrict__ sWi, u16* __restrict__ sWip,
                            const float* __restrict__ sWo, u16* __restrict__ sWop,
                            const float* __restrict__ Wi, u16* __restrict__ Wip,
                            const float* __restrict__ Wo, u16* __restrict__ Wop) {
  __shared__ float tile[64][65];
  int b = blockIdx.x, tid = threadIdx.x;
  if (b < 1024) {
    int t    = b * 4 + (tid >> 6);
    int lane = tid & 63;
    float acc[E_];
    #pragma unroll
    for (int e = 0; e < E_; e++) acc[e] = 0.f;
    #pragma unroll
    for (int i = 0; i < H_ / 256; i++) {
      int c = i * 256 + lane * 4;
      float4 xv = *(const float4*)(x + (long)t * H_ + c);
      ushort4 u;
      u.x = f2bf(xv.x); u.y = f2bf(xv.y); u.z = f2bf(xv.z); u.w = f2bf(xv.w);
      *(ushort4*)(xb + (long)t * H_ + c) = u;
      #pragma unroll
      for (int e = 0; e < E_; e++) {
        float4 g = *(const float4*)(gw + e * H_ + c);
        acc[e] += xv.x * g.x + xv.y * g.y + xv.z * g.z + xv.w * g.w;
      }
    }
    #pragma unroll
    for (int e = 0; e < E_; e++) {
      #pragma unroll
      for (int s = 32; s > 0; s >>= 1) acc[e] += __shfl_xor(acc[e], s);
    }
    if (lane == 0) {
      float logits[E_], sel[E_];
      #pragma unroll
      for (int e = 0; e < E_; e++) {
        logits[e] = 1.f / (1.f + expf(-acc[e]));
        sel[e]    = logits[e] + bias[e];
      }
      int i0 = 0;
      #pragma unroll
      for (int e = 1; e < E_; e++) if (sel[e] > sel[i0]) i0 = e;
      int i1 = (i0 == 0) ? 1 : 0;
      #pragma unroll
      for (int e = 0; e < E_; e++) if (e != i0 && sel[e] > sel[i1]) i1 = e;
      float w0 = logits[i0], w1 = logits[i1], s = w0 + w1;
      top2e[t * 2 + 0] = i0;  top2w[t * 2 + 0] = w0 / s;
      top2e[t * 2 + 1] = i1;  top2w[t * 2 + 1] = w1 / s;
    }
  } else if (b < 1456) {
    int idx = b - 1024;                   // sWi (2304 x 768): 36 x 12 tiles
    int bx = idx % 36, by = idx / 36;
    pack_direct(sWi, sWip, F2_, H_, bx * 64, by * 64, tid);
  } else if (b < 1672) {
    int idx = b - 1456;                   // sWo (768 x 1152): 12 x 18 tiles
    int bx = idx % 12, by = idx / 12;
    pack_direct(sWo, sWop, H_, I_, bx * 64, by * 64, tid);
  } else if (b < 5128) {
    int idx = b - 1672;                   // Wi_e (768 x 2304): n-tiles 36, k-tiles 12
    int e = idx / 432, rem = idx % 432;
    int bx = rem % 36, by = rem / 36;
    pack_transpose(Wi + (long)e * H_ * F2_, Wip + (long)e * F2_ * H_,
                   F2_, H_, bx * 64, by * 64, tile, tid);
  } else {
    int idx = b - 5128;                   // Wo_e (1152 x 768): n-tiles 12, k-tiles 18
    int e = idx / 216, rem = idx % 216;
    int bx = rem % 12, by = rem / 12;
    pack_transpose(Wo + (long)e * I_ * H_, Wop + (long)e * H_ * I_,
                   H_, I_, bx * 64, by * 64, tile, tid);
  }
}

// ---------------- build lists: 8 blocks (one per expert), zero atomics ----------------
__global__ void build_lists(const int* __restrict__ top2e, const float* __restrict__ top2w,
                            int* __restrict__ counts, int* __restrict__ offs,
                            int* __restrict__ list, float* __restrict__ wlist,
                            int* __restrict__ pos, int* __restrict__ rbc) {
  __shared__ int scnt[4][E_];
  __shared__ int sq[4];
  __shared__ int soffs[E_];
  int e = blockIdx.x;
  int tid = threadIdx.x, w = tid >> 6, lane = tid & 63;
  const int Q = (2 * T_) / 4;

  int c8[E_];
  #pragma unroll
  for (int q = 0; q < E_; q++) c8[q] = 0;
  for (int i = tid; i < 2 * T_; i += 256) {
    int v = top2e[i];
    #pragma unroll
    for (int q = 0; q < E_; q++) c8[q] += (v == q);
  }
  int qstart = w * Q;
  int ce = 0;
  for (int i = qstart + lane; i < qstart + Q; i += 64) ce += (top2e[i] == e);
  #pragma unroll
  for (int q = 0; q < E_; q++)
    #pragma unroll
    for (int s = 32; s > 0; s >>= 1) c8[q] += __shfl_xor(c8[q], s);
  #pragma unroll
  for (int s = 32; s > 0; s >>= 1) ce += __shfl_xor(ce, s);
  if (lane == 0) {
    #pragma unroll
    for (int q = 0; q < E_; q++) scnt[w][q] = c8[q];
    sq[w] = ce;
  }
  __syncthreads();
  if (tid == 0) {
    int s = 0, rb = 0;
    if (e == 0) rbc[0] = 0;
    #pragma unroll
    for (int q = 0; q < E_; q++) {
      int tot = scnt[0][q] + scnt[1][q] + scnt[2][q] + scnt[3][q];
      soffs[q] = s;
      if (e == 0) {
        counts[q] = tot; offs[q] = s;
        rb += (tot + 127) / 128;
        rbc[q + 1] = rb;
      }
      s += tot;
    }
    if (e == 0) {
      counts[8] = T_; offs[8] = 2 * T_;
      rbc[9] = rb + T_ / 128;
    }
  }
  __syncthreads();
  int base = soffs[e];
  #pragma unroll
  for (int w2 = 0; w2 < 4; w2++) if (w2 < w) base += sq[w2];
  unsigned long long lt = (lane == 63) ? (~0ull >> 1) : ((1ull << lane) - 1);
  for (int i0 = qstart; i0 < qstart + Q; i0 += 64) {
    int s = i0 + lane;
    bool m = (top2e[s] == e);
    unsigned long long mask = __ballot(m);
    if (m) {
      int p = base + __popcll(mask & lt);
      list[p]  = s >> 1;
      wlist[p] = top2w[s];
      pos[s]   = p;
    }
    base += __popcll(mask);
  }
  for (int t = e * (T_ / 8) + tid; t < (e + 1) * (T_ / 8); t += 256) {
    list[2 * T_ + t]  = t;
    wlist[2 * T_ + t] = 1.f;
  }
}

// ---------------- GEMM1 (+fused SiLU): A via LDS, B packed coalesced direct ----------------
__global__ __launch_bounds__(256, 2)
void gemm_act_all(const u16* __restrict__ A, const u16* __restrict__ Wip,
                  const u16* __restrict__ sWip, u16* __restrict__ act,
                  const int* __restrict__ list, const float* __restrict__ wlist,
                  const int* __restrict__ counts, const int* __restrict__ offsets,
                  const int* __restrict__ rbc) {
  __shared__ __align__(16) u16 As[128 * 64];

  int id = blockIdx.x;
  int r = id / 24, xblk = id - r * 24;
  if (xblk >= 18) return;
  if (r >= rbc[9]) return;
  int z = 0;
  while (r >= rbc[z + 1]) z++;
  int y = r - rbc[z];
  int cnt = counts[z], off = offsets[z];
  int row0 = y * 128;
  const u16* Bp = (z == 8) ? sWip : (Wip + (long)z * F2_ * H_);
  int n0 = xblk * 64;

  int tid  = threadIdx.x;
  int lane = tid & 63, wv = tid >> 6;
  int wr   = wv >> 1, wc = wv & 1;
  int half = lane & 15, quad = lane >> 4;

  int rA  = tid >> 3;
  int lc8 = ((tid & 7) ^ (rA & 7)) * 8;
  const u16* ap[4];
  #pragma unroll
  for (int n = 0; n < 4; n++) {
    int rr = min(row0 + rA + n * 32, cnt - 1);
    ap[n] = A + (long)list[off + rr] * H_ + lc8;
  }
  const int KT1 = H_ / 32;   // 24 panels along K
  const u16* bb[2][2];
  #pragma unroll
  for (int h = 0; h < 2; h++)
    #pragma unroll
    for (int j = 0; j < 2; j++) {
      long nt = (h * I_ + n0 + wc * 32 + j * 16) >> 4;
      bb[h][j] = Bp + (nt * KT1 * 64 + lane) * 8;
    }

  floatx4 acc[2][4][2];
  #pragma unroll
  for (int q = 0; q < 2; q++)
    #pragma unroll
    for (int i = 0; i < 4; i++)
      #pragma unroll
      for (int j = 0; j < 2; j++) acc[q][i][j] = (floatx4)0.f;

  for (int k0 = 0; k0 < H_; k0 += 64) {
    int kt = k0 >> 5;
    bf16x8 bq[2][2][2];
    #pragma unroll
    for (int kk = 0; kk < 2; kk++)
      #pragma unroll
      for (int h = 0; h < 2; h++)
        #pragma unroll
        for (int j = 0; j < 2; j++)
          bq[kk][h][j] = *(const bf16x8*)(bb[h][j] + (kt + kk) * 512);
    if (k0) __syncthreads();
    #pragma unroll
    for (int n = 0; n < 4; n++) gld16(As + (n * 256 + tid) * 8, ap[n] + k0);
    __syncthreads();
    #pragma unroll
    for (int kk = 0; kk < 2; kk++) {
      int cs = ((kk * 4 + quad) ^ (half & 7)) * 8;
      bf16x8 a[4];
      #pragma unroll
      for (int i = 0; i < 4; i++)
        a[i] = *(const bf16x8*)(As + (wr * 64 + i * 16 + half) * 64 + cs);
      #pragma unroll
      for (int i = 0; i < 4; i++)
        #pragma unroll
        for (int q = 0; q < 2; q++)
          #pragma unroll
          for (int j = 0; j < 2; j++)
            acc[q][i][j] = __builtin_amdgcn_mfma_f32_16x16x32_bf16(a[i], bq[kk][q][j], acc[q][i][j], 0, 0, 0);
    }
  }

  bool sh = (z == 8);
  #pragma unroll
  for (int i = 0; i < 4; i++) {
    #pragma unroll
    for (int rr = 0; rr < 4; rr++) {
      int g = row0 + wr * 64 + i * 16 + quad * 4 + rr;
      if (g < cnt) {
        float w = wlist[off + g];
        #pragma unroll
        for (int j = 0; j < 2; j++) {
          float va = acc[0][i][j][rr];
          float vb = acc[1][i][j][rr];
          float zz = sh ? va : vb;
          float o  = sh ? vb : va;
          float sg = zz / (1.f + expf(-zz));
          float v  = sg * o * w;
          int col  = n0 + wc * 32 + j * 16 + half;
          act[(long)(off + g) * I_ + col] = f2bf(v);
        }
      }
    }
  }
}

// ---------------- GEMM2: A via LDS, B packed coalesced direct ----------------
__global__ __launch_bounds__(256, 2)
void gemm_out_all(const u16* __restrict__ A, const u16* __restrict__ Wop,
                  const u16* __restrict__ sWop, float* __restrict__ out,
                  float* __restrict__ eobuf,
                  const int* __restrict__ counts, const int* __restrict__ offsets,
                  const int* __restrict__ rbc) {
  __shared__ __align__(16) u16 As[128 * 64];

  int id = blockIdx.x;
  int r = id >> 3, xblk = id & 7;
  if (xblk >= 6) return;
  if (r >= rbc[9]) return;
  int z = 0;
  while (r >= rbc[z + 1]) z++;
  int y = r - rbc[z];
  int cnt = counts[z], off = offsets[z];
  int row0 = y * 128;
  const u16* Bp = (z == 8) ? sWop : (Wop + (long)z * H_ * I_);
  int n0 = xblk * 128;

  int tid  = threadIdx.x;
  int lane = tid & 63, wv = tid >> 6;
  int wr   = wv >> 1, wc = wv & 1;
  int half = lane & 15, quad = lane >> 4;

  int rA  = tid >> 3;
  int lc8 = ((tid & 7) ^ (rA & 7)) * 8;
  const u16* ap[4];
  #pragma unroll
  for (int n = 0; n < 4; n++) {
    long rr = off + min(row0 + rA + n * 32, cnt - 1);
    ap[n] = A + rr * I_ + lc8;
  }
  const int KT2 = I_ / 32;   // 36 panels along K
  const u16* bb[4];
  #pragma unroll
  for (int j = 0; j < 4; j++) {
    long nt = (n0 + wc * 64 + j * 16) >> 4;
    bb[j] = Bp + (nt * KT2 * 64 + lane) * 8;
  }

  floatx4 acc[4][4];
  #pragma unroll
  for (int i = 0; i < 4; i++)
    #pragma unroll
    for (int j = 0; j < 4; j++) acc[i][j] = (floatx4)0.f;

  for (int k0 = 0; k0 < I_; k0 += 64) {
    int kt = k0 >> 5;
    bf16x8 bq[2][4];
    #pragma unroll
    for (int kk = 0; kk < 2; kk++)
      #pragma unroll
      for (int j = 0; j < 4; j++)
        bq[kk][j] = *(const bf16x8*)(bb[j] + (kt + kk) * 512);
    if (k0) __syncthreads();
    #pragma unroll
    for (int n = 0; n < 4; n++) gld16(As + (n * 256 + tid) * 8, ap[n] + k0);
    __syncthreads();
    #pragma unroll
    for (int kk = 0; kk < 2; kk++) {
      int cs = ((kk * 4 + quad) ^ (half & 7)) * 8;
      bf16x8 a[4];
      #pragma unroll
      for (int i = 0; i < 4; i++)
        a[i] = *(const bf16x8*)(As + (wr * 64 + i * 16 + half) * 64 + cs);
      #pragma unroll
      for (int i = 0; i < 4; i++)
        #pragma unroll
        for (int j = 0; j < 4; j++)
          acc[i][j] = __builtin_amdgcn_mfma_f32_16x16x32_bf16(a[i], bq[kk][j], acc[i][j], 0, 0, 0);
    }
  }

  bool sh = (z == 8);
  #pragma unroll
  for (int i = 0; i < 4; i++) {
    #pragma unroll
    for (int rr = 0; rr < 4; rr++) {
      int g = row0 + wr * 64 + i * 16 + quad * 4 + rr;
      if (g < cnt) {
        float* orow = sh ? (out + (long)g * H_) : (eobuf + (long)(off + g) * H_);
        #pragma unroll
        for (int j = 0; j < 4; j++) {
          int col = n0 + wc * 64 + j * 16 + half;
          orow[col] = acc[i][j][rr];
        }
      }
    }
  }
}

// ---------------- final: out[t] += eobuf[pos0[t]] + eobuf[pos1[t]] ----------------
__global__ void final_reduce(float* __restrict__ out, const float* __restrict__ eobuf,
                             const int* __restrict__ pos) {
  int gid = blockIdx.x * 256 + threadIdx.x;
  int t = gid / (H_ / 4), c = (gid % (H_ / 4)) * 4;
  int p0 = pos[t * 2], p1 = pos[t * 2 + 1];
  float4 a = *(const float4*)(out   + (long)t  * H_ + c);
  float4 b = *(const float4*)(eobuf + (long)p0 * H_ + c);
  float4 d = *(const float4*)(eobuf + (long)p1 * H_ + c);
  a.x += b.x + d.x; a.y += b.y + d.y; a.z += b.z + d.z; a.w += b.w + d.w;
  *(float4*)(out + (long)t * H_ + c) = a;
}

extern "C" void kernel_launch(void* const* d_in, const int* in_sizes, int n_in,
                              void* d_out, int out_size, void* d_ws, size_t ws_size,
                              hipStream_t stream) {
  const float* x      = (const float*)d_in[0];
  const float* gate_w = (const float*)d_in[1];
  const float* bias   = (const float*)d_in[2];
  const float* Wi     = (const float*)d_in[3];
  const float* Wo     = (const float*)d_in[4];
  const float* sWi    = (const float*)d_in[5];
  const float* sWo    = (const float*)d_in[6];
  float* out          = (float*)d_out;

  char* ws = (char*)d_ws;
  size_t o = 0;
  auto alloc = [&](size_t bytes) -> void* {
    o = (o + 255) & ~(size_t)255;
    void* p = ws + o;
    o += bytes;
    return p;
  };
  u16*   xb    = (u16*)  alloc((size_t)T_ * H_ * 2);
  u16*   sWip  = (u16*)  alloc((size_t)F2_ * H_ * 2);
  u16*   sWop  = (u16*)  alloc((size_t)H_ * I_ * 2);
  u16*   Wip   = (u16*)  alloc((size_t)E_ * F2_ * H_ * 2);   // 28.3 MB
  u16*   Wop   = (u16*)  alloc((size_t)E_ * H_ * I_ * 2);
  u16*   act   = (u16*)  alloc((size_t)3 * T_ * I_ * 2);
  int*   top2e = (int*)  alloc((size_t)T_ * 2 * 4);
  float* top2w = (float*)alloc((size_t)T_ * 2 * 4);
  int*   count = (int*)  alloc(16 * 4);
  int*   offs  = (int*)  alloc(16 * 4);
  int*   list  = (int*)  alloc((size_t)3 * T_ * 4);
  float* wlist = (float*)alloc((size_t)3 * T_ * 4);
  int*   pos   = (int*)  alloc((size_t)2 * T_ * 4);
  int*   rbc   = (int*)  alloc(16 * 4);
  // eobuf (8192*768*4 = 25.2 MB) aliases Wip (28.3 MB): Wip dead after gemm_act_all.
  float* eobuf = (float*)Wip;

  prep_kernel<<<6856, 256, 0, stream>>>(x, gate_w, bias, top2e, top2w, xb,
                                        sWi, sWip, sWo, sWop, Wi, Wip, Wo, Wop);
  build_lists<<<E_, 256, 0, stream>>>(top2e, top2w, count, offs, list, wlist, pos, rbc);

  gemm_act_all<<<RBMAX * 24, 256, 0, stream>>>(xb, Wip, sWip, act, list, wlist,
                                               count, offs, rbc);
  gemm_out_all<<<RBMAX * 8, 256, 0, stream>>>(act, Wop, sWop, out, eobuf,
                                              count, offs, rbc);
  final_reduce<<<(T_ * (H_ / 4)) / 256, 256, 0, stream>>>(out, eobuf, pos);
}

// Round 8
// 305.337 us; speedup vs baseline: 1.3299x; 1.0233x over previous
//
#include <hip/hip_runtime.h>
#include <stdint.h>

#define E_  8
#define H_  768
#define I_  1152
#define T_  4096
#define F2_ (2*I_)   // 2304
#define RBMAX 104    // worst-case total 128-row blocks: <=72 expert + 32 shared

typedef unsigned short u16;
typedef __attribute__((ext_vector_type(8))) __bf16 bf16x8;
typedef __attribute__((ext_vector_type(8))) unsigned short u16x8;
typedef __attribute__((ext_vector_type(4))) float floatx4;

typedef const void __attribute__((address_space(1))) as1_void;
typedef void __attribute__((address_space(3))) as3_void;

__device__ __forceinline__ void gld16(void* lds, const void* g) {
  __builtin_amdgcn_global_load_lds((as1_void*)g, (as3_void*)lds, 16, 0, 0);
}

__device__ __forceinline__ u16 f2bf(float f) {
  union { float f; unsigned int i; } v; v.f = f;
  unsigned int r = v.i + 0x7FFF + ((v.i >> 16) & 1);  // round-to-nearest-even
  return (u16)(r >> 16);
}

// ===== packed-B layout: B(n,k), panel = (n>>4)*(K/32)+(k>>5),
// lane = (n&15) | (((k>>3)&3)<<4), elem = k&7; offset = (panel*64+lane)*8+elem.
// Panel = 1KB, exactly one wave-wide MFMA B-fragment: loads/staging are linear.

__device__ __forceinline__ void pack_direct(const float* __restrict__ src,
                                            u16* __restrict__ dst, int N, int K,
                                            int n0, int k0, int tid) {
  int n = tid & 63, kc2 = tid >> 6;
  int KT = K >> 5;
  #pragma unroll
  for (int pass = 0; pass < 2; pass++) {
    int kc = kc2 + pass * 4;
    int k  = k0 + kc * 8;
    const float* sp = src + (long)(n0 + n) * K + k;
    float4 v0 = *(const float4*)sp;
    float4 v1 = *(const float4*)(sp + 4);
    u16x8 u;
    u[0]=f2bf(v0.x); u[1]=f2bf(v0.y); u[2]=f2bf(v0.z); u[3]=f2bf(v0.w);
    u[4]=f2bf(v1.x); u[5]=f2bf(v1.y); u[6]=f2bf(v1.z); u[7]=f2bf(v1.w);
    long p = (long)((n0 + n) >> 4) * KT + (k >> 5);
    int lane = (n & 15) | ((kc & 3) << 4);
    *(u16x8*)(dst + (p * 64 + lane) * 8) = u;
  }
}

__device__ __forceinline__ void pack_transpose(const float* __restrict__ src,
                                               u16* __restrict__ dst, int N, int K,
                                               int n0, int k0, float (*tile)[65], int tid) {
  int cc = tid & 63, rr = tid >> 6;
  #pragma unroll
  for (int p = 0; p < 16; p++)
    tile[rr + p * 4][cc] = src[(long)(k0 + rr + p * 4) * N + n0 + cc];
  __syncthreads();
  int n = tid & 63, kc2 = tid >> 6;
  int KT = K >> 5;
  #pragma unroll
  for (int pass = 0; pass < 2; pass++) {
    int kc = kc2 + pass * 4;
    int k  = k0 + kc * 8;
    u16x8 u;
    #pragma unroll
    for (int e = 0; e < 8; e++) u[e] = f2bf(tile[kc * 8 + e][n]);
    long p = (long)((n0 + n) >> 4) * KT + (k >> 5);
    int lane = (n & 15) | ((kc & 3) << 4);
    *(u16x8*)(dst + (p * 64 + lane) * 8) = u;
  }
}

// ================= fused prep: gate + weight packing =================
__global__ void prep_kernel(const float* __restrict__ x, const float* __restrict__ gw,
                            const float* __restrict__ bias,
                            int* __restrict__ top2e, float* __restrict__ top2w,
                            u16* __restrict__ xb,
                            const float* __restrict__ sWi, u16* __restrict__ sWip,
                            const float* __restrict__ sWo, u16* __restrict__ sWop,
                            const float* __restrict__ Wi, u16* __restrict__ Wip,
                            const float* __restrict__ Wo, u16* __restrict__ Wop) {
  __shared__ float tile[64][65];
  int b = blockIdx.x, tid = threadIdx.x;
  if (b < 1024) {
    int t    = b * 4 + (tid >> 6);
    int lane = tid & 63;
    float acc[E_];
    #pragma unroll
    for (int e = 0; e < E_; e++) acc[e] = 0.f;
    #pragma unroll
    for (int i = 0; i < H_ / 256; i++) {
      int c = i * 256 + lane * 4;
      float4 xv = *(const float4*)(x + (long)t * H_ + c);
      ushort4 u;
      u.x = f2bf(xv.x); u.y = f2bf(xv.y); u.z = f2bf(xv.z); u.w = f2bf(xv.w);
      *(ushort4*)(xb + (long)t * H_ + c) = u;
      #pragma unroll
      for (int e = 0; e < E_; e++) {
        float4 g = *(const float4*)(gw + e * H_ + c);
        acc[e] += xv.x * g.x + xv.y * g.y + xv.z * g.z + xv.w * g.w;
      }
    }
    #pragma unroll
    for (int e = 0; e < E_; e++) {
      #pragma unroll
      for (int s = 32; s > 0; s >>= 1) acc[e] += __shfl_xor(acc[e], s);
    }
    if (lane == 0) {
      float logits[E_], sel[E_];
      #pragma unroll
      for (int e = 0; e < E_; e++) {
        logits[e] = 1.f / (1.f + expf(-acc[e]));
        sel[e]    = logits[e] + bias[e];
      }
      int i0 = 0;
      #pragma unroll
      for (int e = 1; e < E_; e++) if (sel[e] > sel[i0]) i0 = e;
      int i1 = (i0 == 0) ? 1 : 0;
      #pragma unroll
      for (int e = 0; e < E_; e++) if (e != i0 && sel[e] > sel[i1]) i1 = e;
      float w0 = logits[i0], w1 = logits[i1], s = w0 + w1;
      top2e[t * 2 + 0] = i0;  top2w[t * 2 + 0] = w0 / s;
      top2e[t * 2 + 1] = i1;  top2w[t * 2 + 1] = w1 / s;
    }
  } else if (b < 1456) {
    int idx = b - 1024;                   // sWi (2304 x 768): 36 x 12 tiles
    int bx = idx % 36, by = idx / 36;
    pack_direct(sWi, sWip, F2_, H_, bx * 64, by * 64, tid);
  } else if (b < 1672) {
    int idx = b - 1456;                   // sWo (768 x 1152): 12 x 18 tiles
    int bx = idx % 12, by = idx / 12;
    pack_direct(sWo, sWop, H_, I_, bx * 64, by * 64, tid);
  } else if (b < 5128) {
    int idx = b - 1672;                   // Wi_e: pack (F2 x H) from (H x F2)
    int e = idx / 432, rem = idx % 432;
    int bx = rem % 36, by = rem / 36;
    pack_transpose(Wi + (long)e * H_ * F2_, Wip + (long)e * F2_ * H_,
                   F2_, H_, bx * 64, by * 64, tile, tid);
  } else {
    int idx = b - 5128;                   // Wo_e: pack (H x I) from (I x H)
    int e = idx / 216, rem = idx % 216;
    int bx = rem % 12, by = rem / 12;
    pack_transpose(Wo + (long)e * I_ * H_, Wop + (long)e * H_ * I_,
                   H_, I_, bx * 64, by * 64, tile, tid);
  }
}

// ---------------- build lists: 8 blocks (one per expert), zero atomics ----------------
__global__ void build_lists(const int* __restrict__ top2e, const float* __restrict__ top2w,
                            int* __restrict__ counts, int* __restrict__ offs,
                            int* __restrict__ list, float* __restrict__ wlist,
                            int* __restrict__ pos, int* __restrict__ rbc) {
  __shared__ int scnt[4][E_];
  __shared__ int sq[4];
  __shared__ int soffs[E_];
  int e = blockIdx.x;
  int tid = threadIdx.x, w = tid >> 6, lane = tid & 63;
  const int Q = (2 * T_) / 4;

  int c8[E_];
  #pragma unroll
  for (int q = 0; q < E_; q++) c8[q] = 0;
  for (int i = tid; i < 2 * T_; i += 256) {
    int v = top2e[i];
    #pragma unroll
    for (int q = 0; q < E_; q++) c8[q] += (v == q);
  }
  int qstart = w * Q;
  int ce = 0;
  for (int i = qstart + lane; i < qstart + Q; i += 64) ce += (top2e[i] == e);
  #pragma unroll
  for (int q = 0; q < E_; q++)
    #pragma unroll
    for (int s = 32; s > 0; s >>= 1) c8[q] += __shfl_xor(c8[q], s);
  #pragma unroll
  for (int s = 32; s > 0; s >>= 1) ce += __shfl_xor(ce, s);
  if (lane == 0) {
    #pragma unroll
    for (int q = 0; q < E_; q++) scnt[w][q] = c8[q];
    sq[w] = ce;
  }
  __syncthreads();
  if (tid == 0) {
    int s = 0, rb = 0;
    if (e == 0) rbc[0] = 0;
    #pragma unroll
    for (int q = 0; q < E_; q++) {
      int tot = scnt[0][q] + scnt[1][q] + scnt[2][q] + scnt[3][q];
      soffs[q] = s;
      if (e == 0) {
        counts[q] = tot; offs[q] = s;
        rb += (tot + 127) / 128;
        rbc[q + 1] = rb;
      }
      s += tot;
    }
    if (e == 0) {
      counts[8] = T_; offs[8] = 2 * T_;
      rbc[9] = rb + T_ / 128;
    }
  }
  __syncthreads();
  int base = soffs[e];
  #pragma unroll
  for (int w2 = 0; w2 < 4; w2++) if (w2 < w) base += sq[w2];
  unsigned long long lt = (lane == 63) ? (~0ull >> 1) : ((1ull << lane) - 1);
  for (int i0 = qstart; i0 < qstart + Q; i0 += 64) {
    int s = i0 + lane;
    bool m = (top2e[s] == e);
    unsigned long long mask = __ballot(m);
    if (m) {
      int p = base + __popcll(mask & lt);
      list[p]  = s >> 1;
      wlist[p] = top2w[s];
      pos[s]   = p;
    }
    base += __popcll(mask);
  }
  for (int t = e * (T_ / 8) + tid; t < (e + 1) * (T_ / 8); t += 256) {
    list[2 * T_ + t]  = t;
    wlist[2 * T_ + t] = 1.f;
  }
}

// ---------------- GEMM1 (+fused SiLU): A + packed-B both via global_load_lds ----------------
__global__ __launch_bounds__(256, 4)
void gemm_act_all(const u16* __restrict__ A, const u16* __restrict__ Wip,
                  const u16* __restrict__ sWip, u16* __restrict__ act,
                  const int* __restrict__ list, const float* __restrict__ wlist,
                  const int* __restrict__ counts, const int* __restrict__ offsets,
                  const int* __restrict__ rbc) {
  __shared__ __align__(16) u16 As[128 * 64];
  __shared__ __align__(16) u16 Bs[16 * 512];   // 16 panels x 1KB

  int id = blockIdx.x;
  int r = id / 24, xblk = id - r * 24;
  if (xblk >= 18) return;
  if (r >= rbc[9]) return;
  int z = 0;
  while (r >= rbc[z + 1]) z++;
  int y = r - rbc[z];
  int cnt = counts[z], off = offsets[z];
  int row0 = y * 128;
  const u16* Bp = (z == 8) ? sWip : (Wip + (long)z * F2_ * H_);
  int n0 = xblk * 64;

  int tid  = threadIdx.x;
  int lane = tid & 63, wv = tid >> 6;
  int wr   = wv >> 1, wc = wv & 1;
  int half = lane & 15, quad = lane >> 4;

  // A staging (XOR swizzle on source chunk)
  int rA  = tid >> 3;
  int lc8 = ((tid & 7) ^ (rA & 7)) * 8;
  const u16* ap[4];
  #pragma unroll
  for (int n = 0; n < 4; n++) {
    int rr = min(row0 + rA + n * 32, cnt - 1);
    ap[n] = A + (long)list[off + rr] * H_ + lc8;
  }
  // B staging: wave wv stages panels p=wv*4+i; panel p = [kk][h][jn]
  const int KT1 = H_ / 32;   // 24
  const u16* bsrc[4];
  u16* bdst[4];
  #pragma unroll
  for (int i = 0; i < 4; i++) {
    int p  = wv * 4 + i;
    int kk = p >> 3, h = (p >> 2) & 1, jn = p & 3;
    long nt = ((h * I_ + n0) >> 4) + jn;
    bsrc[i] = Bp + ((nt * KT1 + kk) * 64 + lane) * 8;
    bdst[i] = Bs + p * 512 + lane * 8;
  }

  floatx4 acc[2][4][2];
  #pragma unroll
  for (int q = 0; q < 2; q++)
    #pragma unroll
    for (int i = 0; i < 4; i++)
      #pragma unroll
      for (int j = 0; j < 2; j++) acc[q][i][j] = (floatx4)0.f;

  for (int k0 = 0; k0 < H_; k0 += 64) {
    if (k0) __syncthreads();
    #pragma unroll
    for (int n = 0; n < 4; n++) gld16(As + (n * 256 + tid) * 8, ap[n] + k0);
    #pragma unroll
    for (int i = 0; i < 4; i++) gld16(bdst[i], bsrc[i] + (long)k0 * 16);
    __syncthreads();
    #pragma unroll
    for (int kk = 0; kk < 2; kk++) {
      int cs = ((kk * 4 + quad) ^ (half & 7)) * 8;
      bf16x8 a[4], bq[2][2];
      #pragma unroll
      for (int i = 0; i < 4; i++)
        a[i] = *(const bf16x8*)(As + (wr * 64 + i * 16 + half) * 64 + cs);
      #pragma unroll
      for (int h = 0; h < 2; h++)
        #pragma unroll
        for (int j = 0; j < 2; j++)
          bq[h][j] = *(const bf16x8*)(Bs + ((kk * 8 + h * 4 + wc * 2 + j) * 64 + lane) * 8);
      #pragma unroll
      for (int i = 0; i < 4; i++)
        #pragma unroll
        for (int q = 0; q < 2; q++)
          #pragma unroll
          for (int j = 0; j < 2; j++)
            acc[q][i][j] = __builtin_amdgcn_mfma_f32_16x16x32_bf16(a[i], bq[q][j], acc[q][i][j], 0, 0, 0);
    }
  }

  bool sh = (z == 8);
  #pragma unroll
  for (int i = 0; i < 4; i++) {
    #pragma unroll
    for (int rr = 0; rr < 4; rr++) {
      int g = row0 + wr * 64 + i * 16 + quad * 4 + rr;
      if (g < cnt) {
        float w = wlist[off + g];
        #pragma unroll
        for (int j = 0; j < 2; j++) {
          float va = acc[0][i][j][rr];
          float vb = acc[1][i][j][rr];
          float zz = sh ? va : vb;
          float o  = sh ? vb : va;
          float sg = zz / (1.f + expf(-zz));
          float v  = sg * o * w;
          int col  = n0 + wc * 32 + j * 16 + half;
          act[(long)(off + g) * I_ + col] = f2bf(v);
        }
      }
    }
  }
}

// ---------------- GEMM2: A + packed-B via global_load_lds, plain stores ----------------
__global__ __launch_bounds__(256, 4)
void gemm_out_all(const u16* __restrict__ A, const u16* __restrict__ Wop,
                  const u16* __restrict__ sWop, float* __restrict__ out,
                  float* __restrict__ eobuf,
                  const int* __restrict__ counts, const int* __restrict__ offsets,
                  const int* __restrict__ rbc) {
  __shared__ __align__(16) u16 As[128 * 64];
  __shared__ __align__(16) u16 Bs[16 * 512];

  int id = blockIdx.x;
  int r = id >> 3, xblk = id & 7;
  if (xblk >= 6) return;
  if (r >= rbc[9]) return;
  int z = 0;
  while (r >= rbc[z + 1]) z++;
  int y = r - rbc[z];
  int cnt = counts[z], off = offsets[z];
  int row0 = y * 128;
  const u16* Bp = (z == 8) ? sWop : (Wop + (long)z * H_ * I_);
  int n0 = xblk * 128;

  int tid  = threadIdx.x;
  int lane = tid & 63, wv = tid >> 6;
  int wr   = wv >> 1, wc = wv & 1;
  int half = lane & 15, quad = lane >> 4;

  int rA  = tid >> 3;
  int lc8 = ((tid & 7) ^ (rA & 7)) * 8;
  const u16* ap[4];
  #pragma unroll
  for (int n = 0; n < 4; n++) {
    long rr = off + min(row0 + rA + n * 32, cnt - 1);
    ap[n] = A + rr * I_ + lc8;
  }
  const int KT2 = I_ / 32;   // 36
  const u16* bsrc[4];
  u16* bdst[4];
  #pragma unroll
  for (int i = 0; i < 4; i++) {
    int p  = wv * 4 + i;
    int kk = p >> 3, jn = p & 7;
    long nt = (n0 >> 4) + jn;
    bsrc[i] = Bp + ((nt * KT2 + kk) * 64 + lane) * 8;
    bdst[i] = Bs + p * 512 + lane * 8;
  }

  floatx4 acc[4][4];
  #pragma unroll
  for (int i = 0; i < 4; i++)
    #pragma unroll
    for (int j = 0; j < 4; j++) acc[i][j] = (floatx4)0.f;

  for (int k0 = 0; k0 < I_; k0 += 64) {
    if (k0) __syncthreads();
    #pragma unroll
    for (int n = 0; n < 4; n++) gld16(As + (n * 256 + tid) * 8, ap[n] + k0);
    #pragma unroll
    for (int i = 0; i < 4; i++) gld16(bdst[i], bsrc[i] + (long)k0 * 16);
    __syncthreads();
    #pragma unroll
    for (int kk = 0; kk < 2; kk++) {
      int cs = ((kk * 4 + quad) ^ (half & 7)) * 8;
      bf16x8 a[4], b[4];
      #pragma unroll
      for (int i = 0; i < 4; i++)
        a[i] = *(const bf16x8*)(As + (wr * 64 + i * 16 + half) * 64 + cs);
      #pragma unroll
      for (int j = 0; j < 4; j++)
        b[j] = *(const bf16x8*)(Bs + ((kk * 8 + wc * 4 + j) * 64 + lane) * 8);
      #pragma unroll
      for (int i = 0; i < 4; i++)
        #pragma unroll
        for (int j = 0; j < 4; j++)
          acc[i][j] = __builtin_amdgcn_mfma_f32_16x16x32_bf16(a[i], b[j], acc[i][j], 0, 0, 0);
    }
  }

  bool sh = (z == 8);
  #pragma unroll
  for (int i = 0; i < 4; i++) {
    #pragma unroll
    for (int rr = 0; rr < 4; rr++) {
      int g = row0 + wr * 64 + i * 16 + quad * 4 + rr;
      if (g < cnt) {
        float* orow = sh ? (out + (long)g * H_) : (eobuf + (long)(off + g) * H_);
        #pragma unroll
        for (int j = 0; j < 4; j++) {
          int col = n0 + wc * 64 + j * 16 + half;
          orow[col] = acc[i][j][rr];
        }
      }
    }
  }
}

// ---------------- final: out[t] += eobuf[pos0[t]] + eobuf[pos1[t]] ----------------
__global__ void final_reduce(float* __restrict__ out, const float* __restrict__ eobuf,
                             const int* __restrict__ pos) {
  int gid = blockIdx.x * 256 + threadIdx.x;
  int t = gid / (H_ / 4), c = (gid % (H_ / 4)) * 4;
  int p0 = pos[t * 2], p1 = pos[t * 2 + 1];
  float4 a = *(const float4*)(out   + (long)t  * H_ + c);
  float4 b = *(const float4*)(eobuf + (long)p0 * H_ + c);
  float4 d = *(const float4*)(eobuf + (long)p1 * H_ + c);
  a.x += b.x + d.x; a.y += b.y + d.y; a.z += b.z + d.z; a.w += b.w + d.w;
  *(float4*)(out + (long)t * H_ + c) = a;
}

extern "C" void kernel_launch(void* const* d_in, const int* in_sizes, int n_in,
                              void* d_out, int out_size, void* d_ws, size_t ws_size,
                              hipStream_t stream) {
  const float* x      = (const float*)d_in[0];
  const float* gate_w = (const float*)d_in[1];
  const float* bias   = (const float*)d_in[2];
  const float* Wi     = (const float*)d_in[3];
  const float* Wo     = (const float*)d_in[4];
  const float* sWi    = (const float*)d_in[5];
  const float* sWo    = (const float*)d_in[6];
  float* out          = (float*)d_out;

  char* ws = (char*)d_ws;
  size_t o = 0;
  auto alloc = [&](size_t bytes) -> void* {
    o = (o + 255) & ~(size_t)255;
    void* p = ws + o;
    o += bytes;
    return p;
  };
  u16*   xb    = (u16*)  alloc((size_t)T_ * H_ * 2);
  u16*   sWip  = (u16*)  alloc((size_t)F2_ * H_ * 2);
  u16*   sWop  = (u16*)  alloc((size_t)H_ * I_ * 2);
  u16*   Wip   = (u16*)  alloc((size_t)E_ * F2_ * H_ * 2);   // 28.3 MB
  u16*   Wop   = (u16*)  alloc((size_t)E_ * H_ * I_ * 2);
  u16*   act   = (u16*)  alloc((size_t)3 * T_ * I_ * 2);
  int*   top2e = (int*)  alloc((size_t)T_ * 2 * 4);
  float* top2w = (float*)alloc((size_t)T_ * 2 * 4);
  int*   count = (int*)  alloc(16 * 4);
  int*   offs  = (int*)  alloc(16 * 4);
  int*   list  = (int*)  alloc((size_t)3 * T_ * 4);
  float* wlist = (float*)alloc((size_t)3 * T_ * 4);
  int*   pos   = (int*)  alloc((size_t)2 * T_ * 4);
  int*   rbc   = (int*)  alloc(16 * 4);
  // eobuf (25.2 MB) aliases Wip (28.3 MB): Wip dead after gemm_act_all.
  float* eobuf = (float*)Wip;

  prep_kernel<<<6856, 256, 0, stream>>>(x, gate_w, bias, top2e, top2w, xb,
                                        sWi, sWip, sWo, sWop, Wi, Wip, Wo, Wop);
  build_lists<<<E_, 256, 0, stream>>>(top2e, top2w, count, offs, list, wlist, pos, rbc);

  gemm_act_all<<<RBMAX * 24, 256, 0, stream>>>(xb, Wip, sWip, act, list, wlist,
                                               count, offs, rbc);
  gemm_out_all<<<RBMAX * 8, 256, 0, stream>>>(act, Wop, sWop, out, eobuf,
                                              count, offs, rbc);
  final_reduce<<<(T_ * (H_ / 4)) / 256, 256, 0, stream>>>(out, eobuf, pos);
}